// Round 4
// baseline (921.668 us; speedup 1.0000x reference)
//
#include <hip/hip_runtime.h>

#define T_TOK 1024
#define HD    2048
#define NE    64
#define ID    768
#define TOPK  8

typedef __bf16 bf16x8 __attribute__((ext_vector_type(8)));
typedef float  f32x4  __attribute__((ext_vector_type(4)));

__device__ __forceinline__ bf16x8 cvt8(f32x4 a, f32x4 b) {
  bf16x8 r;
  #pragma unroll
  for (int j = 0; j < 4; ++j) { r[j] = (__bf16)a[j]; r[j + 4] = (__bf16)b[j]; }
  return r;
}

// ---------------------------------------------------------------------------
// Router: fp64 logits -> top-8 -> renormalized weights; per-expert lists;
// x -> bf16.
// ---------------------------------------------------------------------------
__global__ __launch_bounds__(256) void router_kernel(
    const float* __restrict__ x, const float* __restrict__ rw,
    unsigned short* __restrict__ xb_u, float* __restrict__ tw,
    int* __restrict__ counts, int* __restrict__ lists)
{
  __shared__ float  sx[HD];
  __shared__ double slog[NE];
  const int t = blockIdx.x;
  const int tid = threadIdx.x;
  __bf16* xb = (__bf16*)xb_u;

  for (int i = tid; i < HD; i += 256) {
    float v = x[(size_t)t * HD + i];
    sx[i] = v;
    xb[(size_t)t * HD + i] = (__bf16)v;
  }
  __syncthreads();

  const int e = tid >> 2, p = tid & 3;
  const float* rwrow = rw + (size_t)e * HD;
  double acc = 0.0;
  for (int k = p; k < HD; k += 4)
    acc += (double)sx[k] * (double)rwrow[k];
  acc += __shfl_xor(acc, 1, 64);
  acc += __shfl_xor(acc, 2, 64);
  if (p == 0) slog[e] = acc;
  __syncthreads();

  if (tid < 64) {
    double v = slog[tid];
    double selv = -1e300; int seli = 0; double gmax = 0.0;
    #pragma unroll
    for (int k = 0; k < TOPK; ++k) {
      double bv = v; int bi = tid;
      #pragma unroll
      for (int off = 32; off >= 1; off >>= 1) {
        double ov = __shfl_xor(bv, off, 64);
        int    oi = __shfl_xor(bi, off, 64);
        if (ov > bv || (ov == bv && oi < bi)) { bv = ov; bi = oi; }
      }
      if (k == 0) gmax = bv;
      if (tid == k) { selv = bv; seli = bi; }
      if (tid == bi) v = -1e300;
    }
    double e_ = (tid < TOPK) ? exp(selv - gmax) : 0.0;
    double s = e_;
    #pragma unroll
    for (int off = 32; off >= 1; off >>= 1) s += __shfl_xor(s, off, 64);
    if (tid < TOPK) {
      int slot = t * TOPK + tid;
      tw[slot] = (float)(e_ / s);
      int pos = atomicAdd(&counts[seli], 1);
      lists[seli * T_TOK + pos] = slot;
    }
  }
}

// ---------------------------------------------------------------------------
// GEMM1: pure-register streaming, NO LDS, NO barriers.
// Block = 256 thr = 4 waves. Wave (h = w&1, cg = w>>1): 16 cols of G AND U
// (cols n0 + cg*16 ..+15), m-frags 2f+h (f=0..7) over M=256 padded rows.
// K-loop BK=32: W(t+1) issued at top, cvt at bottom; A-frags direct from L2.
// Grid 1536 = 8 XCD chunks of 192 (24 blocks/expert).
// ---------------------------------------------------------------------------
__global__ __launch_bounds__(256, 3) void gemm1_kernel(
    const unsigned short* __restrict__ xb_u,
    const float* __restrict__ gw, const float* __restrict__ uw,
    const int* __restrict__ counts, const int* __restrict__ lists,
    unsigned short* __restrict__ hb_u)
{
  const char* xbp = (const char*)xb_u;
  __bf16* hb = (__bf16*)hb_u;

  const int wg  = blockIdx.x;
  const int idx = wg >> 3;                    // 0..191
  const int e   = (wg & 7) * 8 + idx / 24;
  const int n0  = (idx % 24) * 32;            // over I=768

  const int tid = threadIdx.x, w = tid >> 6, lane = tid & 63;
  const int h = w & 1, cg = w >> 1;
  const int n_e = counts[e];

  // per-frag slots and A byte-offsets (frag f covers rows (2f+h)*16 ..+15)
  int slot[8]; unsigned aoff[8];
  #pragma unroll
  for (int f = 0; f < 8; ++f) {
    int row = (2 * f + h) * 16 + (lane & 15);
    slot[f] = (row < n_e) ? lists[e * T_TOK + row] : 0;
    aoff[f] = (unsigned)((slot[f] >> 3) * (HD * 2)) + ((lane >> 4) * 16);
  }

  // W byte-offsets from expert base (row = output col, k-contiguous)
  const char* gp = (const char*)(gw + (size_t)e * ID * HD);
  const char* up = (const char*)(uw + (size_t)e * ID * HD);
  unsigned woff = (unsigned)((n0 + cg * 16 + (lane & 15)) * (HD * 4)) + ((lane >> 4) * 32);

  f32x4 accg[8], accu[8];
  const f32x4 vzero = {0.f, 0.f, 0.f, 0.f};
  #pragma unroll
  for (int f = 0; f < 8; ++f) { accg[f] = vzero; accu[f] = vzero; }

  // prologue: W(0) -> cvt
  f32x4 g0 = *(const f32x4*)(gp + woff), g1 = *(const f32x4*)(gp + woff + 16);
  f32x4 u0 = *(const f32x4*)(up + woff), u1 = *(const f32x4*)(up + woff + 16);
  bf16x8 gc = cvt8(g0, g1), uc = cvt8(u0, u1);
  unsigned wo = woff + 128;
  unsigned ao = 0;

  #pragma unroll 1
  for (int t = 0; t < HD / 32; ++t) {
    f32x4 gn0, gn1, un0, un1;
    const bool pf = (t < HD / 32 - 1);
    if (pf) {                                  // issue W(t+1) early
      gn0 = *(const f32x4*)(gp + wo); gn1 = *(const f32x4*)(gp + wo + 16);
      un0 = *(const f32x4*)(up + wo); un1 = *(const f32x4*)(up + wo + 16);
      wo += 128;
    }
    #pragma unroll
    for (int f = 0; f < 8; ++f) if ((2 * f + h) * 16 < n_e) {
      bf16x8 aF = *(const bf16x8*)(xbp + (size_t)(aoff[f] + ao));
      accg[f] = __builtin_amdgcn_mfma_f32_16x16x32_bf16(aF, gc, accg[f], 0, 0, 0);
      accu[f] = __builtin_amdgcn_mfma_f32_16x16x32_bf16(aF, uc, accu[f], 0, 0, 0);
    }
    ao += 64;
    if (pf) { gc = cvt8(gn0, gn1); uc = cvt8(un0, un1); }  // cvt W(t+1) late
  }

  // epilogue: silu(g)*u -> bf16 hidden_buf
  #pragma unroll
  for (int f = 0; f < 8; ++f) if ((2 * f + h) * 16 < n_e) {
    #pragma unroll
    for (int j = 0; j < 4; ++j) {
      int q = (lane >> 4) * 4 + j;
      int row = (2 * f + h) * 16 + q;
      int s = __shfl(slot[f], q, 64);
      if (row < n_e) {
        float gv = accg[f][j], uv = accu[f][j];
        float hv = (gv / (1.0f + expf(-gv))) * uv;
        hb[(size_t)s * ID + (size_t)(n0 + cg * 16 + (lane & 15))] = (__bf16)hv;
      }
    }
  }
}

// ---------------------------------------------------------------------------
// GEMM2: hidden[M x 768] @ down^T, same pure-register streaming structure.
// Block = 4 waves; wave = 16 H-cols x 8 interleaved m-frags. Grid 4096
// (64 blocks/expert). Weighted atomic scatter to out.
// ---------------------------------------------------------------------------
__global__ __launch_bounds__(256, 4) void gemm2_kernel(
    const unsigned short* __restrict__ hb_u,
    const float* __restrict__ dw,
    const int* __restrict__ counts, const int* __restrict__ lists,
    const float* __restrict__ tw,
    float* __restrict__ out)
{
  const char* hbp = (const char*)hb_u;

  const int wg  = blockIdx.x;
  const int idx = wg >> 3;                    // 0..511
  const int e   = (wg & 7) * 8 + idx / 64;
  const int n0  = (idx % 64) * 32;            // over H=2048

  const int tid = threadIdx.x, w = tid >> 6, lane = tid & 63;
  const int h = w & 1, cg = w >> 1;
  const int n_e = counts[e];

  int slot[8]; unsigned aoff[8];
  #pragma unroll
  for (int f = 0; f < 8; ++f) {
    int row = (2 * f + h) * 16 + (lane & 15);
    slot[f] = (row < n_e) ? lists[e * T_TOK + row] : 0;
    aoff[f] = (unsigned)(slot[f] * (ID * 2)) + ((lane >> 4) * 16);
  }

  const char* wp = (const char*)(dw + (size_t)e * HD * ID);
  unsigned woff = (unsigned)((n0 + cg * 16 + (lane & 15)) * (ID * 4)) + ((lane >> 4) * 32);

  f32x4 acc[8];
  const f32x4 vzero = {0.f, 0.f, 0.f, 0.f};
  #pragma unroll
  for (int f = 0; f < 8; ++f) acc[f] = vzero;

  f32x4 d0 = *(const f32x4*)(wp + woff), d1 = *(const f32x4*)(wp + woff + 16);
  bf16x8 dc = cvt8(d0, d1);
  unsigned wo = woff + 128;
  unsigned ao = 0;

  #pragma unroll 1
  for (int t = 0; t < ID / 32; ++t) {
    f32x4 dn0, dn1;
    const bool pf = (t < ID / 32 - 1);
    if (pf) {
      dn0 = *(const f32x4*)(wp + wo); dn1 = *(const f32x4*)(wp + wo + 16);
      wo += 128;
    }
    #pragma unroll
    for (int f = 0; f < 8; ++f) if ((2 * f + h) * 16 < n_e) {
      bf16x8 aF = *(const bf16x8*)(hbp + (size_t)(aoff[f] + ao));
      acc[f] = __builtin_amdgcn_mfma_f32_16x16x32_bf16(aF, dc, acc[f], 0, 0, 0);
    }
    ao += 64;
    if (pf) dc = cvt8(dn0, dn1);
  }

  #pragma unroll
  for (int f = 0; f < 8; ++f) if ((2 * f + h) * 16 < n_e) {
    #pragma unroll
    for (int j = 0; j < 4; ++j) {
      int q = (lane >> 4) * 4 + j;
      int row = (2 * f + h) * 16 + q;
      int s = __shfl(slot[f], q, 64);
      if (row < n_e) {
        float wv = tw[s];
        int token = s >> 3;
        atomicAdd(out + (size_t)token * HD + (size_t)(n0 + cg * 16 + (lane & 15)),
                  wv * acc[f][j]);
      }
    }
  }
}

// ---------------------------------------------------------------------------
// Launcher. ws layout: xb bf16 | tw | counts | lists | hidden_buf bf16.
// ---------------------------------------------------------------------------
extern "C" void kernel_launch(void* const* d_in, const int* in_sizes, int n_in,
                              void* d_out, int out_size, void* d_ws, size_t ws_size,
                              hipStream_t stream) {
  const float* x  = (const float*)d_in[0];
  const float* rw = (const float*)d_in[1];
  const float* gw = (const float*)d_in[2];
  const float* uw = (const float*)d_in[3];
  const float* dw = (const float*)d_in[4];
  float* out = (float*)d_out;

  char* ws = (char*)d_ws;
  const size_t XB_OFF  = 0;
  const size_t TW_OFF  = XB_OFF + (size_t)T_TOK * HD * 2;
  const size_t CNT_OFF = TW_OFF + (size_t)T_TOK * TOPK * 4;
  const size_t LST_OFF = CNT_OFF + 256;
  const size_t HB_OFF  = LST_OFF + (size_t)NE * T_TOK * 4;

  unsigned short* xb  = (unsigned short*)(ws + XB_OFF);
  float*          tw  = (float*)(ws + TW_OFF);
  int*            cnt = (int*)(ws + CNT_OFF);
  int*            lst = (int*)(ws + LST_OFF);
  unsigned short* hb  = (unsigned short*)(ws + HB_OFF);

  hipMemsetAsync(cnt, 0, 256, stream);
  hipMemsetAsync(d_out, 0, (size_t)T_TOK * HD * sizeof(float), stream);

  router_kernel<<<T_TOK, 256, 0, stream>>>(x, rw, xb, tw, cnt, lst);
  gemm1_kernel<<<1536, 256, 0, stream>>>(xb, gw, uw, cnt, lst, hb);
  gemm2_kernel<<<4096, 256, 0, stream>>>(hb, dw, cnt, lst, tw, out);
}

// Round 5
// 493.073 us; speedup vs baseline: 1.8692x; 1.8692x over previous
//
#include <hip/hip_runtime.h>

#define T_TOK 1024
#define HD    2048
#define NE    64
#define ID    768
#define TOPK  8

typedef __bf16 bf16x8 __attribute__((ext_vector_type(8)));
typedef __bf16 bf16x4 __attribute__((ext_vector_type(4)));
typedef float  f32x4  __attribute__((ext_vector_type(4)));

#define LGKM0 asm volatile("s_waitcnt lgkmcnt(0)" ::: "memory")
#define BAR() __builtin_amdgcn_s_barrier()

__device__ __forceinline__ int swz(int r) { return (r ^ (r >> 2)) & 3; }

// ---------------------------------------------------------------------------
// Router: fp64 logits -> top-8 -> renormalized weights; per-expert lists;
// x -> bf16.
// ---------------------------------------------------------------------------
__global__ __launch_bounds__(256) void router_kernel(
    const float* __restrict__ x, const float* __restrict__ rw,
    unsigned short* __restrict__ xb_u, float* __restrict__ tw,
    int* __restrict__ counts, int* __restrict__ lists)
{
  __shared__ float  sx[HD];
  __shared__ double slog[NE];
  const int t = blockIdx.x;
  const int tid = threadIdx.x;
  __bf16* xb = (__bf16*)xb_u;

  for (int i = tid; i < HD; i += 256) {
    float v = x[(size_t)t * HD + i];
    sx[i] = v;
    xb[(size_t)t * HD + i] = (__bf16)v;
  }
  __syncthreads();

  const int e = tid >> 2, p = tid & 3;
  const float* rwrow = rw + (size_t)e * HD;
  double acc = 0.0;
  for (int k = p; k < HD; k += 4)
    acc += (double)sx[k] * (double)rwrow[k];
  acc += __shfl_xor(acc, 1, 64);
  acc += __shfl_xor(acc, 2, 64);
  if (p == 0) slog[e] = acc;
  __syncthreads();

  if (tid < 64) {
    double v = slog[tid];
    double selv = -1e300; int seli = 0; double gmax = 0.0;
    #pragma unroll
    for (int k = 0; k < TOPK; ++k) {
      double bv = v; int bi = tid;
      #pragma unroll
      for (int off = 32; off >= 1; off >>= 1) {
        double ov = __shfl_xor(bv, off, 64);
        int    oi = __shfl_xor(bi, off, 64);
        if (ov > bv || (ov == bv && oi < bi)) { bv = ov; bi = oi; }
      }
      if (k == 0) gmax = bv;
      if (tid == k) { selv = bv; seli = bi; }
      if (tid == bi) v = -1e300;
    }
    double e_ = (tid < TOPK) ? exp(selv - gmax) : 0.0;
    double s = e_;
    #pragma unroll
    for (int off = 32; off >= 1; off >>= 1) s += __shfl_xor(s, off, 64);
    if (tid < TOPK) {
      int slot = t * TOPK + tid;
      tw[slot] = (float)(e_ / s);
      int pos = atomicAdd(&counts[seli], 1);
      lists[seli * T_TOK + pos] = slot;
    }
  }
}

// ---------------------------------------------------------------------------
// GEMM1: BM=256, BN=64 i-cols (dual gate+up), BK=32, 512 thr (8 waves 2Mx4N).
// Full reg-staged double-buffer pipeline: ds_write X(t) / issue X(t+1) /
// lgkmcnt(0)+s_barrier (NO vmcnt at barrier -> loads stay in flight) /
// ds_read frags / MFMA. One barrier per K-tile.
// ---------------------------------------------------------------------------
__global__ __launch_bounds__(512, 4) void gemm1_kernel(
    const unsigned short* __restrict__ xb_u,
    const float* __restrict__ gw, const float* __restrict__ uw,
    const int* __restrict__ counts, const int* __restrict__ lists,
    unsigned short* __restrict__ hb_u)
{
  __shared__ __bf16 sA[2][256 * 32];   // [row][k] 64B rows, chunk-swizzled
  __shared__ __bf16 sG[2][64 * 32];
  __shared__ __bf16 sU[2][64 * 32];
  __shared__ int    sSlot[256];

  const __bf16* xb = (const __bf16*)xb_u;
  __bf16* hb = (__bf16*)hb_u;

  // 768 blocks = 8 XCD chunks of 96 (12 n-tiles x 8 experts per XCD chunk)
  const int wg  = blockIdx.x;
  const int idx = wg >> 3;
  const int e   = (wg & 7) * 8 + idx / 12;
  const int n0  = (idx % 12) * 64;
  const int tid = threadIdx.x, wid = tid >> 6, lane = tid & 63;
  const int mr = wid >> 2, nc = wid & 3;
  const int n_e = counts[e];

  // A staging: 2 ops/thread, op j covers rows wid*32 + j*16 + (lane>>2)
  const int rA0 = wid * 32 + (lane >> 2);
  const int rA1 = rA0 + 16;
  const int cA  = lane & 3;
  const int aDst0 = rA0 * 64 + ((cA ^ swz(rA0)) << 4);
  const int aDst1 = rA1 * 64 + ((cA ^ swz(rA1)) << 4);

  // W staging: 1 f32x4/thread per matrix; thread -> (col, 16B-k-chunk)
  const int cW = tid >> 3, kc = tid & 7;
  const float* gSrc = gw + ((size_t)e * ID + n0 + cW) * HD + kc * 4;
  const float* uSrc = uw + ((size_t)e * ID + n0 + cW) * HD + kc * 4;
  const int wDst = cW * 64 + (((kc >> 1) ^ swz(cW)) << 4) + (kc & 1) * 8;

  // W frag geometry (per wave)
  const int colW  = nc * 16 + (lane & 15);
  const int wFoff = colW * 64 + (((lane >> 4) ^ swz(colW)) << 4);

  for (int m0 = 0; m0 < n_e; m0 += 256) {
    __syncthreads();
    if (tid < 256) sSlot[tid] = (m0 + tid < n_e) ? lists[e * T_TOK + m0 + tid] : 0;
    __syncthreads();

    const __bf16* aSrc0 = xb + (size_t)(sSlot[rA0] >> 3) * HD + cA * 8;
    const __bf16* aSrc1 = xb + (size_t)(sSlot[rA1] >> 3) * HD + cA * 8;

    f32x4 accg[8], accu[8];
    const f32x4 vzero = {0.f, 0.f, 0.f, 0.f};
    #pragma unroll
    for (int q = 0; q < 8; ++q) { accg[q] = vzero; accu[q] = vzero; }

    const int rows_here = n_e - m0 - mr * 128;   // wave-uniform

    // prologue: load X(0) into regs
    bf16x8 aR0 = *(const bf16x8*)aSrc0;
    bf16x8 aR1 = *(const bf16x8*)aSrc1;
    f32x4  gR  = *(const f32x4*)gSrc;
    f32x4  uR  = *(const f32x4*)uSrc;

    #pragma unroll 1
    for (int t = 0; t < HD / 32; ++t) {
      char* bA = (char*)&sA[t & 1][0];
      char* bG = (char*)&sG[t & 1][0];
      char* bU = (char*)&sU[t & 1][0];

      // ds_write X(t) (implicit vmcnt wait on regs loaded one tile ago)
      *(bf16x8*)(bA + aDst0) = aR0;
      *(bf16x8*)(bA + aDst1) = aR1;
      bf16x4 gv, uv;
      #pragma unroll
      for (int q = 0; q < 4; ++q) { gv[q] = (__bf16)gR[q]; uv[q] = (__bf16)uR[q]; }
      *(bf16x4*)(bG + wDst) = gv;
      *(bf16x4*)(bU + wDst) = uv;

      // issue X(t+1) -> same regs (stays in flight across the barrier)
      const int kn = (t < HD / 32 - 1 ? t + 1 : t) * 32;
      aR0 = *(const bf16x8*)(aSrc0 + kn);
      aR1 = *(const bf16x8*)(aSrc1 + kn);
      gR  = *(const f32x4*)(gSrc + kn);
      uR  = *(const f32x4*)(uSrc + kn);

      LGKM0; BAR();   // ds_writes visible; vmcnt NOT drained

      // frags + MFMA
      bf16x8 gF = *(const bf16x8*)(bG + wFoff);
      bf16x8 uF = *(const bf16x8*)(bU + wFoff);
      #pragma unroll
      for (int q = 0; q < 8; ++q) if (q * 16 < rows_here) {
        int row = mr * 128 + q * 16 + (lane & 15);
        bf16x8 aF = *(const bf16x8*)(bA + row * 64 + (((lane >> 4) ^ swz(row)) << 4));
        accg[q] = __builtin_amdgcn_mfma_f32_16x16x32_bf16(aF, gF, accg[q], 0, 0, 0);
        accu[q] = __builtin_amdgcn_mfma_f32_16x16x32_bf16(aF, uF, accu[q], 0, 0, 0);
      }
    }

    // epilogue: silu(g)*u -> bf16 hidden_buf
    #pragma unroll
    for (int q = 0; q < 8; ++q) if (q * 16 < rows_here) {
      #pragma unroll
      for (int j = 0; j < 4; ++j) {
        int row = mr * 128 + q * 16 + (lane >> 4) * 4 + j;
        if (m0 + row < n_e) {
          int s = sSlot[row];
          float g = accg[q][j], u = accu[q][j];
          float h = (g / (1.0f + expf(-g))) * u;
          hb[(size_t)s * ID + (size_t)(n0 + colW)] = (__bf16)h;
        }
      }
    }
  }
}

// ---------------------------------------------------------------------------
// GEMM2: BM=256, BN=64 H-cols, BK=32, K=768 (24 tiles). Same pipeline;
// weighted atomic scatter to out.
// ---------------------------------------------------------------------------
__global__ __launch_bounds__(512, 4) void gemm2_kernel(
    const unsigned short* __restrict__ hb_u,
    const float* __restrict__ dw,
    const int* __restrict__ counts, const int* __restrict__ lists,
    const float* __restrict__ tw,
    float* __restrict__ out)
{
  __shared__ __bf16 sA[2][256 * 32];
  __shared__ __bf16 sD[2][64 * 32];
  __shared__ int    sSlot[256];

  const __bf16* hbuf = (const __bf16*)hb_u;

  // 2048 blocks = 8 XCD chunks of 256 (32 n-tiles x 8 experts)
  const int wg  = blockIdx.x;
  const int idx = wg >> 3;
  const int e   = (wg & 7) * 8 + idx / 32;
  const int n0  = (idx % 32) * 64;
  const int tid = threadIdx.x, wid = tid >> 6, lane = tid & 63;
  const int mr = wid >> 2, nc = wid & 3;
  const int n_e = counts[e];

  const int rA0 = wid * 32 + (lane >> 2);
  const int rA1 = rA0 + 16;
  const int cA  = lane & 3;
  const int aDst0 = rA0 * 64 + ((cA ^ swz(rA0)) << 4);
  const int aDst1 = rA1 * 64 + ((cA ^ swz(rA1)) << 4);

  const int cW = tid >> 3, kc = tid & 7;
  const float* dSrc = dw + ((size_t)e * HD + n0 + cW) * ID + kc * 4;
  const int wDst = cW * 64 + (((kc >> 1) ^ swz(cW)) << 4) + (kc & 1) * 8;

  const int colW  = nc * 16 + (lane & 15);
  const int wFoff = colW * 64 + (((lane >> 4) ^ swz(colW)) << 4);

  for (int m0 = 0; m0 < n_e; m0 += 256) {
    __syncthreads();
    if (tid < 256) sSlot[tid] = (m0 + tid < n_e) ? lists[e * T_TOK + m0 + tid] : 0;
    __syncthreads();

    const __bf16* aSrc0 = hbuf + (size_t)sSlot[rA0] * ID + cA * 8;
    const __bf16* aSrc1 = hbuf + (size_t)sSlot[rA1] * ID + cA * 8;

    f32x4 acc[8];
    const f32x4 vzero = {0.f, 0.f, 0.f, 0.f};
    #pragma unroll
    for (int q = 0; q < 8; ++q) acc[q] = vzero;

    const int rows_here = n_e - m0 - mr * 128;

    bf16x8 aR0 = *(const bf16x8*)aSrc0;
    bf16x8 aR1 = *(const bf16x8*)aSrc1;
    f32x4  dR  = *(const f32x4*)dSrc;

    #pragma unroll 1
    for (int t = 0; t < ID / 32; ++t) {
      char* bA = (char*)&sA[t & 1][0];
      char* bD = (char*)&sD[t & 1][0];

      *(bf16x8*)(bA + aDst0) = aR0;
      *(bf16x8*)(bA + aDst1) = aR1;
      bf16x4 dv;
      #pragma unroll
      for (int q = 0; q < 4; ++q) dv[q] = (__bf16)dR[q];
      *(bf16x4*)(bD + wDst) = dv;

      const int kn = (t < ID / 32 - 1 ? t + 1 : t) * 32;
      aR0 = *(const bf16x8*)(aSrc0 + kn);
      aR1 = *(const bf16x8*)(aSrc1 + kn);
      dR  = *(const f32x4*)(dSrc + kn);

      LGKM0; BAR();

      bf16x8 dF = *(const bf16x8*)(bD + wFoff);
      #pragma unroll
      for (int q = 0; q < 8; ++q) if (q * 16 < rows_here) {
        int row = mr * 128 + q * 16 + (lane & 15);
        bf16x8 aF = *(const bf16x8*)(bA + row * 64 + (((lane >> 4) ^ swz(row)) << 4));
        acc[q] = __builtin_amdgcn_mfma_f32_16x16x32_bf16(aF, dF, acc[q], 0, 0, 0);
      }
    }

    #pragma unroll
    for (int q = 0; q < 8; ++q) if (q * 16 < rows_here) {
      #pragma unroll
      for (int j = 0; j < 4; ++j) {
        int row = mr * 128 + q * 16 + (lane >> 4) * 4 + j;
        if (m0 + row < n_e) {
          int s = sSlot[row];
          int token = s >> 3;
          float w = tw[s];
          atomicAdd(out + (size_t)token * HD + (size_t)(n0 + colW),
                    w * acc[q][j]);
        }
      }
    }
  }
}

// ---------------------------------------------------------------------------
// Launcher. ws: xb bf16 | tw | counts | lists | hidden_buf bf16 (~17 MB).
// ---------------------------------------------------------------------------
extern "C" void kernel_launch(void* const* d_in, const int* in_sizes, int n_in,
                              void* d_out, int out_size, void* d_ws, size_t ws_size,
                              hipStream_t stream) {
  const float* x  = (const float*)d_in[0];
  const float* rw = (const float*)d_in[1];
  const float* gw = (const float*)d_in[2];
  const float* uw = (const float*)d_in[3];
  const float* dw = (const float*)d_in[4];
  float* out = (float*)d_out;

  char* ws = (char*)d_ws;
  const size_t XB_OFF  = 0;
  const size_t TW_OFF  = XB_OFF + (size_t)T_TOK * HD * 2;
  const size_t CNT_OFF = TW_OFF + (size_t)T_TOK * TOPK * 4;
  const size_t LST_OFF = CNT_OFF + 256;
  const size_t HB_OFF  = LST_OFF + (size_t)NE * T_TOK * 4;

  unsigned short* xb  = (unsigned short*)(ws + XB_OFF);
  float*          tw  = (float*)(ws + TW_OFF);
  int*            cnt = (int*)(ws + CNT_OFF);
  int*            lst = (int*)(ws + LST_OFF);
  unsigned short* hb  = (unsigned short*)(ws + HB_OFF);

  hipMemsetAsync(cnt, 0, 256, stream);
  hipMemsetAsync(d_out, 0, (size_t)T_TOK * HD * sizeof(float), stream);

  router_kernel<<<T_TOK, 256, 0, stream>>>(x, rw, xb, tw, cnt, lst);
  gemm1_kernel<<<768, 512, 0, stream>>>(xb, gw, uw, cnt, lst, hb);
  gemm2_kernel<<<2048, 512, 0, stream>>>(hb, dw, cnt, lst, tw, out);
}